// Round 10
// baseline (153.752 us; speedup 1.0000x reference)
//
#include <hip/hip_runtime.h>

// GraphSAGE 2-layer + global mean pool.
// N=100000 nodes, E=1e6 edges, 64 -> 64 (relu) -> 128 channels, 128 graphs.
// Pipeline: bucket-count -> bucket-scan -> binA (coarse bucket sort) ->
// binB (per-bucket (quartile,row) sort -> src CSR + rpq offsets) ->
// sage conv1/conv2: QUARTILE-PHASED ownership gather (4 phases, each phase's
// src working set ~3.2MB = L2-resident) + MFMA; conv2 fuses register
// shfl-reduce mean-pool epilogue. -> cnt -> finalize.

#define IN_CH       64
#define OUT_CH      128
#define N_GRAPHS    128
#define NBUCK_SHIFT 9
#define BROWS       512      // rows per coarse bucket
#define NQ          4        // src quartiles (per-quartile feat slice < 4MB L2)

typedef __attribute__((ext_vector_type(8))) short bf16x8;   // 8 bf16 = 4 VGPR
typedef __attribute__((ext_vector_type(4))) float f32x4;

__device__ __forceinline__ unsigned short f2b(float f) {    // RNE float->bf16
    unsigned int u = __float_as_uint(f);
    return (unsigned short)((u + 0x7FFFu + ((u >> 16) & 1u)) >> 16);
}

// pack 8 consecutive f32 (LDS) * inv -> bf16x8
__device__ __forceinline__ bf16x8 pack8(const float* p, float inv) {
    union { bf16x8 v; unsigned int u[4]; } r;
#pragma unroll
    for (int i = 0; i < 4; i++) {
        unsigned int lo = f2b(p[2 * i] * inv);
        unsigned int hi = f2b(p[2 * i + 1] * inv);
        r.u[i] = (hi << 16) | lo;
    }
    return r.v;
}

// ---------------- prep: x->bf16 and packed bf16 weights wc[oc][k<64:Wl | k>=64:Wr] ----------------
__global__ __launch_bounds__(256) void prep_kernel(const float* __restrict__ x,
                                                   const float* __restrict__ Wl1,
                                                   const float* __restrict__ Wr1,
                                                   const float* __restrict__ Wl2,
                                                   const float* __restrict__ Wr2,
                                                   unsigned short* __restrict__ xb,
                                                   unsigned short* __restrict__ wc1,
                                                   unsigned short* __restrict__ wc2,
                                                   int n4) {
    int i = blockIdx.x * 256 + threadIdx.x;
    if (i < n4) {
        float4 v = ((const float4*)x)[i];
        ushort4 o;
        o.x = f2b(v.x); o.y = f2b(v.y); o.z = f2b(v.z); o.w = f2b(v.w);
        ((ushort4*)xb)[i] = o;
    } else {
        int j = i - n4;
        if (j < 64 * 128) {
            int oc = j >> 7, k = j & 127;
            float v = (k < 64) ? Wl1[oc * 64 + k] : Wr1[oc * 64 + k - 64];
            wc1[j] = f2b(v);
        } else if (j < 64 * 128 + 128 * 128) {
            int jj = j - 64 * 128;
            int oc = jj >> 7, k = jj & 127;
            float v = (k < 64) ? Wl2[oc * 64 + k] : Wr2[oc * 64 + k - 64];
            wc2[jj] = f2b(v);
        }
    }
}

// ---------------- bucket totals (LDS count, few global adds) ----------------
__global__ __launch_bounds__(256) void bucket_count_kernel(const int* __restrict__ dst,
                                                           int* __restrict__ btot, int E) {
    constexpr int CH = 4096;
    __shared__ int c[256];
    const int tid = threadIdx.x;
    const int e0 = blockIdx.x * CH;
    const int n = min(CH, E - e0);
    c[tid] = 0;
    __syncthreads();
    for (int i = tid; i < n; i += 256)
        atomicAdd(&c[dst[e0 + i] >> NBUCK_SHIFT], 1);
    __syncthreads();
    if (c[tid] > 0) atomicAdd(&btot[tid], c[tid]);
}

// ---------------- bucket scan -> bbase, bcur ----------------
__global__ __launch_bounds__(256) void bucket_scan_kernel(const int* __restrict__ btot,
                                                          int* __restrict__ bbase,
                                                          int* __restrict__ bcur,
                                                          int nbuck, int E) {
    __shared__ int t[256];
    int tid = threadIdx.x;
    int v = (tid < nbuck) ? btot[tid] : 0;
    int val = v;
    t[tid] = val;
    __syncthreads();
    for (int o = 1; o < 256; o <<= 1) {
        int a = (tid >= o) ? t[tid - o] : 0;
        __syncthreads();
        val += a;
        t[tid] = val;
        __syncthreads();
    }
    int ex = val - v;                          // exclusive
    if (tid <= nbuck) bbase[tid] = ex;         // bbase[nbuck] == E
    if (tid < nbuck) bcur[tid] = ex;
}

// ---------------- pass A: bin edges into coarse buckets, coalesced run flushes ----------------
// packed staged value: (local_row<<17) | src   (src < 2^17, local_row < 512)
__global__ __launch_bounds__(256) void binA_kernel(const int* __restrict__ src,
                                                   const int* __restrict__ dst,
                                                   int* __restrict__ bcur,
                                                   int* __restrict__ staged, int E) {
    constexpr int CH = 4096;
    __shared__ int cnt[256];
    __shared__ int cur[256];
    __shared__ int gbase[256];
    __shared__ int lstart[256];
    __shared__ int tmp[256];
    __shared__ int sortedv[CH];
    __shared__ unsigned char sortedb[CH];

    const int tid = threadIdx.x;
    const int e0 = blockIdx.x * CH;
    const int n = min(CH, E - e0);

    cnt[tid] = 0;
    __syncthreads();
    for (int i = tid; i < n; i += 256)
        atomicAdd(&cnt[dst[e0 + i] >> NBUCK_SHIFT], 1);
    __syncthreads();
    int v = cnt[tid];
    int inc = v;
    tmp[tid] = inc;
    __syncthreads();
    for (int o = 1; o < 256; o <<= 1) {
        int t = (tid >= o) ? tmp[tid - o] : 0;
        __syncthreads();
        inc += t;
        tmp[tid] = inc;
        __syncthreads();
    }
    lstart[tid] = inc - v;
    cur[tid] = inc - v;
    if (v > 0) gbase[tid] = atomicAdd(&bcur[tid], v);
    __syncthreads();
    for (int i = tid; i < n; i += 256) {
        int d = dst[e0 + i], s = src[e0 + i];
        int b = d >> NBUCK_SHIFT;
        int p = atomicAdd(&cur[b], 1);
        sortedv[p] = ((d & (BROWS - 1)) << 17) | s;
        sortedb[p] = (unsigned char)b;
    }
    __syncthreads();
    for (int i = tid; i < n; i += 256) {
        int b = sortedb[i];
        staged[gbase[b] + (i - lstart[b])] = sortedv[i];
    }
}

// ---------------- pass B: per-bucket (quartile,row) sort -> src CSR + rpq ----------------
// bin key = q*BROWS + lrow (2048 bins); rpq[b*2048 + bin] = global start offset.
__global__ __launch_bounds__(256) void binB_kernel(const int* __restrict__ staged,
                                                   const int* __restrict__ bbase,
                                                   int* __restrict__ csr,
                                                   int* __restrict__ rpq,
                                                   float qscale) {
    constexpr int CAP  = 8192;                 // bucket mean ~5120, sigma ~72
    constexpr int BINS = NQ * BROWS;           // 2048
    __shared__ int cnt[BINS];
    __shared__ int cur[BINS];
    __shared__ int tmp[256];
    __shared__ int sorted[CAP];

    const int tid = threadIdx.x;
    const int b = blockIdx.x;
    const int base = bbase[b];
    const int n = bbase[b + 1] - base;

    for (int k = tid; k < BINS; k += 256) cnt[k] = 0;
    __syncthreads();
    for (int i = tid; i < n; i += 256) {
        int p = staged[base + i];
        int s = p & 0x1FFFF;
        int q = min(NQ - 1, (int)((float)s * qscale));
        atomicAdd(&cnt[q * BROWS + (p >> 17)], 1);
    }
    __syncthreads();
    // exclusive scan of 2048 bins: thread owns 8 serial + block scan of totals
    int loc[8];
    int run = 0;
    const int b8 = tid * 8;
#pragma unroll
    for (int k = 0; k < 8; k++) { loc[k] = run; run += cnt[b8 + k]; }
    int val = run;
    tmp[tid] = val;
    __syncthreads();
    for (int o = 1; o < 256; o <<= 1) {
        int t = (tid >= o) ? tmp[tid - o] : 0;
        __syncthreads();
        val += t;
        tmp[tid] = val;
        __syncthreads();
    }
    int off = val - run;
#pragma unroll
    for (int k = 0; k < 8; k++) {
        int ex = off + loc[k];
        cur[b8 + k] = ex;
        rpq[b * BINS + b8 + k] = base + ex;    // all bins written (0-count ok)
    }
    __syncthreads();
    for (int i = tid; i < n; i += 256) {
        int p = staged[base + i];
        int s = p & 0x1FFFF;
        int q = min(NQ - 1, (int)((float)s * qscale));
        int pos = atomicAdd(&cur[q * BROWS + (p >> 17)], 1);
        if (pos < CAP) sorted[pos] = s;
    }
    __syncthreads();
    for (int i = tid; i < n; i += 256)
        csr[base + i] = sorted[min(i, CAP - 1)];
}

// ---------------- fused SAGE conv, quartile-phased gather ----------------
// Block = 64 dst nodes (one bucket holds exactly 8 blocks). 32 slots (4 waves
// x 8); slot owns 2 rows; its 8 lanes (fl) each load uint4 (8 bf16 feats);
// 4-deep feature pipeline + csr 8-ahead. Gather runs 4 phases; phase q walks
// only src-quartile-q edges (L2-resident slice), flush = non-atomic LDS
// read-add-write (exclusive row ownership). MFMA: K=128 (k<64 neighbor-mean
// tile, k>=64 self from global), B from global. POOL: register epilogue.
template <int OUTC, bool RELU, bool OUT_BF16, bool POOL>
__global__ __launch_bounds__(256, 8) void sage_kernel(
    const unsigned short* __restrict__ featb,  // [N,64] bf16
    const int* __restrict__ csr,               // src, (bucket,q,row)-sorted
    const int* __restrict__ rpq,               // [NBUCK*2048(+)] seg starts
    const unsigned short* __restrict__ wc,     // [OUTC,128] bf16
    const float* __restrict__ bias,            // [OUTC] f32
    void* __restrict__ outp,                   // bf16/f32 [N,OUTC] (unused if POOL)
    const int* __restrict__ batch,             // [N] sorted graph ids (POOL only)
    float* __restrict__ pooled,                // [G,OUTC] f32 (POOL only)
    int N) {
    constexpr int LDA = 68;                    // f32 gather row stride
    __shared__ float agg[64 * LDA];            // 17.4 KB
    __shared__ int rp4[NQ][65];
    __shared__ int bt[64];

    const int tid = threadIdx.x, lane = tid & 63, w = tid >> 6;
    const int base = blockIdx.x * 64;
    const int buck = base >> NBUCK_SHIFT;
    const int l0 = base & (BROWS - 1);

    for (int i = tid; i < 64 * LDA; i += 256) agg[i] = 0.f;
    for (int t = tid; t < NQ * 65; t += 256) {
        int q = t / 65, j = t % 65;
        rp4[q][j] = rpq[buck * (NQ * BROWS) + q * BROWS + l0 + j];
    }
    if (POOL && tid < 64) bt[tid] = batch[min(base + tid, N - 1)];
    __syncthreads();

    // ---- gather: 4 quartile phases; slot owns rows 2sl, 2sl+1 ----
    {
        const int sl = (w << 3) | (lane >> 3); // slot 0..31
        const int fl = lane & 7;               // feature octet
        const uint4* f4 = reinterpret_cast<const uint4*>(featb);
        float a0 = 0.f, a1 = 0.f, a2 = 0.f, a3 = 0.f;
        float a4 = 0.f, a5 = 0.f, a6 = 0.f, a7 = 0.f;

#define FLUSH_ROW_ADD()                                                          \
    do {                                                                         \
        float4* d0 = reinterpret_cast<float4*>(&agg[r * LDA + fl * 8]);          \
        float4 o0 = *d0;                                                         \
        *d0 = make_float4(o0.x + a0, o0.y + a1, o0.z + a2, o0.w + a3);           \
        float4* d1 = reinterpret_cast<float4*>(&agg[r * LDA + fl * 8 + 4]);      \
        float4 o1 = *d1;                                                         \
        *d1 = make_float4(o1.x + a4, o1.y + a5, o1.z + a6, o1.w + a7);           \
        a0 = a1 = a2 = a3 = a4 = a5 = a6 = a7 = 0.f;                             \
    } while (0)

#define PROC(VV, EI)                                                             \
    do {                                                                         \
        if ((EI) < end) {                                                        \
            while ((EI) >= nb) { FLUSH_ROW_ADD(); r++; nb = rpX[r + 1]; }        \
            a0 += __uint_as_float(VV.x << 16);                                   \
            a1 += __uint_as_float(VV.x & 0xffff0000u);                           \
            a2 += __uint_as_float(VV.y << 16);                                   \
            a3 += __uint_as_float(VV.y & 0xffff0000u);                           \
            a4 += __uint_as_float(VV.z << 16);                                   \
            a5 += __uint_as_float(VV.z & 0xffff0000u);                           \
            a6 += __uint_as_float(VV.w << 16);                                   \
            a7 += __uint_as_float(VV.w & 0xffff0000u);                           \
        }                                                                        \
    } while (0)

        for (int q = 0; q < NQ; q++) {
            const int* rpX = rp4[q];
            int r = sl * 2;
            const int e0 = rpX[r];
            const int end = rpX[r + 2];
            if (e0 >= end) continue;
            int nb = rpX[r + 1];
            const int em = end - 1;
            int c4_ = csr[min(e0 + 4, em)], c5_ = csr[min(e0 + 5, em)];
            int c6_ = csr[min(e0 + 6, em)], c7_ = csr[min(e0 + 7, em)];
            uint4 v0 = f4[(size_t)csr[min(e0 + 0, em)] * 8 + fl];
            uint4 v1 = f4[(size_t)csr[min(e0 + 1, em)] * 8 + fl];
            uint4 v2 = f4[(size_t)csr[min(e0 + 2, em)] * 8 + fl];
            uint4 v3 = f4[(size_t)csr[min(e0 + 3, em)] * 8 + fl];

            for (int e = e0; e < end; e += 4) {
                PROC(v0, e + 0);
                v0 = f4[(size_t)c4_ * 8 + fl];
                PROC(v1, e + 1);
                v1 = f4[(size_t)c5_ * 8 + fl];
                PROC(v2, e + 2);
                v2 = f4[(size_t)c6_ * 8 + fl];
                PROC(v3, e + 3);
                v3 = f4[(size_t)c7_ * 8 + fl];
                c4_ = csr[min(e + 8, em)];
                c5_ = csr[min(e + 9, em)];
                c6_ = csr[min(e + 10, em)];
                c7_ = csr[min(e + 11, em)];
            }
            FLUSH_ROW_ADD();                   // add trailing partial for row r
        }
#undef PROC
#undef FLUSH_ROW_ADD
    }
    __syncthreads();

    // ---- MFMA phase ----
    const int hl = lane & 15, sgq = lane >> 4;
    const int row = w * 16 + hl;
    int deg = 0;
#pragma unroll
    for (int q = 0; q < NQ; q++) deg += rp4[q][row + 1] - rp4[q][row];
    float inv = 1.0f / fmaxf((float)deg, 1.0f);
    const float* ar = &agg[row * LDA];
    bf16x8 a[4];
    a[0] = pack8(ar + sgq * 8, inv);           // k 0..31  (neighbor mean)
    a[1] = pack8(ar + 32 + sgq * 8, inv);      // k 32..63
    int nclamp = min(base + row, N - 1);
    const unsigned short* srow = &featb[(size_t)nclamp * 64];
    a[2] = *reinterpret_cast<const bf16x8*>(&srow[sgq * 8]);        // self
    a[3] = *reinterpret_cast<const bf16x8*>(&srow[32 + sgq * 8]);

    // per-lane D-row metadata for the register pool
    int gw0 = 0, gw1 = -1;
    int myg[4];
    bool mval[4];
    if (POOL) {
        gw0 = bt[w * 16];
        gw1 = bt[w * 16 + 15];
#pragma unroll
        for (int r = 0; r < 4; r++) {
            int lrow = w * 16 + sgq * 4 + r;
            mval[r] = (base + lrow) < N;
            myg[r] = bt[lrow];
        }
    }

    constexpr int NT = OUTC / 16;
#pragma unroll
    for (int nt = 0; nt < NT; nt++) {
        f32x4 acc = {0.f, 0.f, 0.f, 0.f};
#pragma unroll
        for (int ks = 0; ks < 4; ks++) {
            bf16x8 b = *reinterpret_cast<const bf16x8*>(
                &wc[(nt * 16 + hl) * 128 + ks * 32 + sgq * 8]);
            acc = __builtin_amdgcn_mfma_f32_16x16x32_bf16(a[ks], b, acc, 0, 0, 0);
        }
        float bv = bias[nt * 16 + hl];
        if (POOL) {
            for (int g = gw0; g <= gw1; g++) {     // wave-uniform, 1-2 iters typ.
                float s = 0.f;
#pragma unroll
                for (int r = 0; r < 4; r++) {
                    float v = acc[r] + bv;
                    if (RELU) v = fmaxf(v, 0.f);
                    s += (mval[r] && myg[r] == g) ? v : 0.f;
                }
                s += __shfl_xor(s, 16);            // reduce across sgq groups
                s += __shfl_xor(s, 32);
                if (lane < 16) atomicAdd(&pooled[g * OUTC + nt * 16 + lane], s);
            }
        } else {
#pragma unroll
            for (int r = 0; r < 4; r++) {
                int node = base + w * 16 + sgq * 4 + r;   // D row = sgq*4+r
                if (node < N) {
                    float v = acc[r] + bv;
                    if (RELU) v = fmaxf(v, 0.f);
                    int oc = nt * 16 + hl;                // D col = lane&15
                    if (OUT_BF16)
                        ((unsigned short*)outp)[(size_t)node * OUTC + oc] = f2b(v);
                    else
                        ((float*)outp)[(size_t)node * OUTC + oc] = v;
                }
            }
        }
    }
}

// ---------------- cnt via binary search over sorted batch ----------------
__global__ __launch_bounds__(128) void cnt_kernel(const int* __restrict__ batch,
                                                  float* __restrict__ cnt, int N) {
    int g = threadIdx.x;
    int lo = 0, hi = N;
    while (lo < hi) { int m = (lo + hi) >> 1; if (batch[m] < g) lo = m + 1; else hi = m; }
    int a = lo;
    lo = 0; hi = N;
    while (lo < hi) { int m = (lo + hi) >> 1; if (batch[m] < g + 1) lo = m + 1; else hi = m; }
    cnt[g] = (float)(lo - a);
}

__global__ __launch_bounds__(256) void finalize_kernel(const float* __restrict__ pooled,
                                                       const float* __restrict__ cnt,
                                                       float* __restrict__ out, int total) {
    int t = blockIdx.x * 256 + threadIdx.x;
    if (t < total) out[t] = pooled[t] / fmaxf(cnt[t >> 7], 1.0f);
}

extern "C" void kernel_launch(void* const* d_in, const int* in_sizes, int n_in,
                              void* d_out, int out_size, void* d_ws, size_t ws_size,
                              hipStream_t stream) {
    const float* x    = (const float*)d_in[0];
    const int*   ei   = (const int*)d_in[1];
    const int*   bat  = (const int*)d_in[2];
    const float* Wl1  = (const float*)d_in[3];
    const float* Wr1  = (const float*)d_in[4];
    const float* b1   = (const float*)d_in[5];
    const float* Wl2  = (const float*)d_in[6];
    const float* Wr2  = (const float*)d_in[7];
    const float* b2   = (const float*)d_in[8];
    float* out = (float*)d_out;

    const int N = in_sizes[0] / IN_CH;        // 100000
    const int E = in_sizes[1] / 2;            // 1000000
    const int* srcp = ei;
    const int* dstp = ei + E;
    const int NBUCK = (N + BROWS - 1) >> NBUCK_SHIFT;   // 196
    const int qdiv  = (N + NQ - 1) / NQ;                // 25000
    const float qscale = 1.0f / (float)qdiv;

    // workspace layout (256B aligned); total ~37 MB
    char* ws = (char*)d_ws;
    size_t off = 0;
    auto alloc = [&](size_t bytes) { size_t p = off; off += (bytes + 255) & ~255ull; return p; };
    size_t btot_off   = alloc(256 * 4);                       // zeroed
    size_t cnt_off    = alloc((size_t)N_GRAPHS * 4);          // zeroed (cnt_kernel overwrites)
    size_t pooled_off = alloc((size_t)N_GRAPHS * OUT_CH * 4); // zeroed
    size_t zero_end   = off;
    size_t bbase_off  = alloc(256 * 4);
    size_t bcur_off   = alloc(256 * 4);
    size_t xb_off     = alloc((size_t)N * 64 * 2);            // x in bf16
    size_t hb_off     = alloc((size_t)N * 64 * 2);            // h in bf16
    size_t rpq_off    = alloc(((size_t)NBUCK * NQ * BROWS + 1) * 4);
    size_t staged_off = alloc((size_t)E * 4);                 // packed (row<<17)|src
    size_t csr_off    = alloc((size_t)E * 4);                 // src only
    size_t wc1_off    = alloc((size_t)64 * 128 * 2);
    size_t wc2_off    = alloc((size_t)128 * 128 * 2);
    (void)ws_size;

    int*            btot   = (int*)(ws + btot_off);
    float*          cnt    = (float*)(ws + cnt_off);
    float*          pooled = (float*)(ws + pooled_off);
    int*            bbase  = (int*)(ws + bbase_off);
    int*            bcur   = (int*)(ws + bcur_off);
    unsigned short* xb     = (unsigned short*)(ws + xb_off);
    unsigned short* hb     = (unsigned short*)(ws + hb_off);
    int*            rpq    = (int*)(ws + rpq_off);
    int*            staged = (int*)(ws + staged_off);
    int*            csr    = (int*)(ws + csr_off);
    unsigned short* wc1    = (unsigned short*)(ws + wc1_off);
    unsigned short* wc2    = (unsigned short*)(ws + wc2_off);

    hipMemsetAsync(ws, 0, zero_end, stream);

    // prep: x->bf16 + packed bf16 weights
    int n4 = N * 64 / 4;
    int prep_total = n4 + 64 * 128 + 128 * 128;
    prep_kernel<<<(prep_total + 255) / 256, 256, 0, stream>>>(
        x, Wl1, Wr1, Wl2, Wr2, xb, wc1, wc2, n4);

    // CSR build
    const int nch = (E + 4095) / 4096;
    bucket_count_kernel<<<nch, 256, 0, stream>>>(dstp, btot, E);
    bucket_scan_kernel<<<1, 256, 0, stream>>>(btot, bbase, bcur, NBUCK, E);
    binA_kernel<<<nch, 256, 0, stream>>>(srcp, dstp, bcur, staged, E);
    binB_kernel<<<NBUCK, 256, 0, stream>>>(staged, bbase, csr, rpq, qscale);

    // fused convs
    const int nblk = (N + 63) / 64;
    sage_kernel<64, true, true, false><<<nblk, 256, 0, stream>>>(
        xb, csr, rpq, wc1, b1, hb, nullptr, nullptr, N);
    sage_kernel<128, false, false, true><<<nblk, 256, 0, stream>>>(
        hb, csr, rpq, wc2, b2, nullptr, bat, pooled, N);

    // finalize
    cnt_kernel<<<1, 128, 0, stream>>>(bat, cnt, N);
    finalize_kernel<<<(N_GRAPHS * OUT_CH + 255) / 256, 256, 0, stream>>>(
        pooled, cnt, out, N_GRAPHS * OUT_CH);
}

// Round 12
// 142.560 us; speedup vs baseline: 1.0785x; 1.0785x over previous
//
#include <hip/hip_runtime.h>

// GraphSAGE 2-layer + global mean pool.
// N=100000 nodes, E=1e6 edges, 64 -> 64 (relu) -> 128 channels, 128 graphs.
// Pipeline: prep(+bucket-count) -> bucket-scan -> binA (coarse bucket sort) ->
// binB (per-bucket row sort -> src CSR + rowptr) -> sage conv1/conv2:
// ownership gather reading an FP8(e4m3) feature table (64B/row = 1 cache line,
// f32 accumulate) + bf16 self-term + MFMA; conv2 fuses register mean-pool.
// -> cnt -> finalize.

#define IN_CH       64
#define OUT_CH      128
#define N_GRAPHS    128
#define NBUCK_SHIFT 9
#define BROWS       512      // rows per coarse bucket

typedef __attribute__((ext_vector_type(8))) short bf16x8;   // 8 bf16 = 4 VGPR
typedef __attribute__((ext_vector_type(4))) float f32x4;
typedef __attribute__((ext_vector_type(2))) float f32x2;

#if defined(__has_builtin)
#  if __has_builtin(__builtin_amdgcn_cvt_pk_f32_fp8) && __has_builtin(__builtin_amdgcn_cvt_pk_fp8_f32)
#    define HAS_HW_FP8 1
#  endif
#endif
#ifndef HAS_HW_FP8
#  define HAS_HW_FP8 0
#endif

__device__ __forceinline__ unsigned short f2b(float f) {    // RNE float->bf16
    unsigned int u = __float_as_uint(f);
    return (unsigned short)((u + 0x7FFFu + ((u >> 16) & 1u)) >> 16);
}

#if !HAS_HW_FP8
__device__ __forceinline__ unsigned fp8_enc(float f) {      // e4m3fn RNE
    unsigned u = __float_as_uint(f);
    unsigned s = (u >> 24) & 0x80u;
    float a = fabsf(f);
    if (a >= 448.f) return s | 0x7Eu;
    if (a < 0.015625f) { int m = (int)rintf(a * 512.f); return s | (unsigned)m; }
    unsigned au = __float_as_uint(a);
    au += 0x7FFFFu + ((au >> 20) & 1u);
    if ((au >> 23) > 135u) return s | 0x7Eu;
    return s | (((au >> 20) & 0x7FFu) - (120u << 3));
}
__device__ __forceinline__ float fp8_dec1(unsigned b) {
    unsigned s = (b & 0x80u) << 24, m = b & 0x7Fu;
    if (m >= 0x08u) return __uint_as_float(s | ((m << 20) + (120u << 23)));
    float v = (float)m * 0.001953125f;
    return __uint_as_float(__float_as_uint(v) | s);
}
#endif

template <bool HI>
__device__ __forceinline__ f32x2 fp8x2_dec(unsigned u) {
#if HAS_HW_FP8
    return __builtin_amdgcn_cvt_pk_f32_fp8((int)u, HI);     // HI is an immediate
#else
    f32x2 r;
    unsigned b0 = HI ? ((u >> 16) & 0xFFu) : (u & 0xFFu);
    unsigned b1 = HI ? (u >> 24) : ((u >> 8) & 0xFFu);
    r.x = fp8_dec1(b0); r.y = fp8_dec1(b1);
    return r;
#endif
}

__device__ __forceinline__ unsigned fp8x4_enc(float a, float b, float c, float d) {
#if HAS_HW_FP8
    int p = __builtin_amdgcn_cvt_pk_fp8_f32(a, b, 0, false);   // literal bools
    p = __builtin_amdgcn_cvt_pk_fp8_f32(c, d, p, true);
    return (unsigned)p;
#else
    return fp8_enc(a) | (fp8_enc(b) << 8) | (fp8_enc(c) << 16) | (fp8_enc(d) << 24);
#endif
}

__device__ __forceinline__ unsigned char f2fp8(float v) {
#if HAS_HW_FP8
    return (unsigned char)(__builtin_amdgcn_cvt_pk_fp8_f32(v, v, 0, false) & 0xFF);
#else
    return (unsigned char)fp8_enc(v);
#endif
}

// pack 8 consecutive f32 (LDS) * inv -> bf16x8
__device__ __forceinline__ bf16x8 pack8(const float* p, float inv) {
    union { bf16x8 v; unsigned int u[4]; } r;
#pragma unroll
    for (int i = 0; i < 4; i++) {
        unsigned int lo = f2b(p[2 * i] * inv);
        unsigned int hi = f2b(p[2 * i + 1] * inv);
        r.u[i] = (hi << 16) | lo;
    }
    return r.v;
}

// ---------------- prep: x -> bf16 + fp8 tables, packed bf16 weights; appended
// blocks do the bucket-count (per-4096-edge LDS histogram -> few global adds).
__global__ __launch_bounds__(256) void prep_kernel(const float* __restrict__ x,
                                                   const float* __restrict__ Wl1,
                                                   const float* __restrict__ Wr1,
                                                   const float* __restrict__ Wl2,
                                                   const float* __restrict__ Wr2,
                                                   unsigned short* __restrict__ xb16,
                                                   unsigned char* __restrict__ xb8,
                                                   unsigned short* __restrict__ wc1,
                                                   unsigned short* __restrict__ wc2,
                                                   const int* __restrict__ dst,
                                                   int* __restrict__ btot,
                                                   int E, int n4, int prep_blocks) {
    if ((int)blockIdx.x >= prep_blocks) {
        constexpr int CH = 4096;
        __shared__ int c[256];
        const int tid = threadIdx.x;
        const int e0 = (blockIdx.x - prep_blocks) * CH;
        const int n = min(CH, E - e0);
        c[tid] = 0;
        __syncthreads();
        for (int i = tid; i < n; i += 256)
            atomicAdd(&c[dst[e0 + i] >> NBUCK_SHIFT], 1);
        __syncthreads();
        if (c[tid] > 0) atomicAdd(&btot[tid], c[tid]);
        return;
    }
    int i = blockIdx.x * 256 + threadIdx.x;
    if (i < n4) {
        float4 v = ((const float4*)x)[i];
        ushort4 o;
        o.x = f2b(v.x); o.y = f2b(v.y); o.z = f2b(v.z); o.w = f2b(v.w);
        ((ushort4*)xb16)[i] = o;
        ((unsigned*)xb8)[i] = fp8x4_enc(v.x, v.y, v.z, v.w);
    } else {
        int j = i - n4;
        if (j < 64 * 128) {
            int oc = j >> 7, k = j & 127;
            float v = (k < 64) ? Wl1[oc * 64 + k] : Wr1[oc * 64 + k - 64];
            wc1[j] = f2b(v);
        } else if (j < 64 * 128 + 128 * 128) {
            int jj = j - 64 * 128;
            int oc = jj >> 7, k = jj & 127;
            float v = (k < 64) ? Wl2[oc * 64 + k] : Wr2[oc * 64 + k - 64];
            wc2[jj] = f2b(v);
        }
    }
}

// ---------------- bucket scan -> bbase, bcur; rowptr[N]=E ----------------
__global__ __launch_bounds__(256) void bucket_scan_kernel(const int* __restrict__ btot,
                                                          int* __restrict__ bbase,
                                                          int* __restrict__ bcur,
                                                          int* __restrict__ rowptr,
                                                          int nbuck, int N, int E) {
    __shared__ int t[256];
    int tid = threadIdx.x;
    int v = (tid < nbuck) ? btot[tid] : 0;
    int val = v;
    t[tid] = val;
    __syncthreads();
    for (int o = 1; o < 256; o <<= 1) {
        int a = (tid >= o) ? t[tid - o] : 0;
        __syncthreads();
        val += a;
        t[tid] = val;
        __syncthreads();
    }
    int ex = val - v;                          // exclusive
    if (tid <= nbuck) bbase[tid] = ex;         // bbase[nbuck] == E
    if (tid < nbuck) bcur[tid] = ex;
    if (tid == 0) rowptr[N] = E;
}

// ---------------- pass A: bin edges into coarse buckets, coalesced run flushes ----------------
// packed staged value: (local_row<<17) | src   (src < 2^17, local_row < 512)
__global__ __launch_bounds__(256) void binA_kernel(const int* __restrict__ src,
                                                   const int* __restrict__ dst,
                                                   int* __restrict__ bcur,
                                                   int* __restrict__ staged, int E) {
    constexpr int CH = 4096;
    __shared__ int cnt[256];
    __shared__ int cur[256];
    __shared__ int gbase[256];
    __shared__ int lstart[256];
    __shared__ int tmp[256];
    __shared__ int sortedv[CH];
    __shared__ unsigned char sortedb[CH];

    const int tid = threadIdx.x;
    const int e0 = blockIdx.x * CH;
    const int n = min(CH, E - e0);

    cnt[tid] = 0;
    __syncthreads();
    for (int i = tid; i < n; i += 256)
        atomicAdd(&cnt[dst[e0 + i] >> NBUCK_SHIFT], 1);
    __syncthreads();
    int v = cnt[tid];
    int inc = v;
    tmp[tid] = inc;
    __syncthreads();
    for (int o = 1; o < 256; o <<= 1) {
        int t = (tid >= o) ? tmp[tid - o] : 0;
        __syncthreads();
        inc += t;
        tmp[tid] = inc;
        __syncthreads();
    }
    lstart[tid] = inc - v;
    cur[tid] = inc - v;
    if (v > 0) gbase[tid] = atomicAdd(&bcur[tid], v);
    __syncthreads();
    for (int i = tid; i < n; i += 256) {
        int d = dst[e0 + i], s = src[e0 + i];
        int b = d >> NBUCK_SHIFT;
        int p = atomicAdd(&cur[b], 1);
        sortedv[p] = ((d & (BROWS - 1)) << 17) | s;
        sortedb[p] = (unsigned char)b;
    }
    __syncthreads();
    for (int i = tid; i < n; i += 256) {
        int b = sortedb[i];
        staged[gbase[b] + (i - lstart[b])] = sortedv[i];
    }
}

// ---------------- pass B: per-bucket row sort -> src CSR + rowptr ----------------
__global__ __launch_bounds__(256) void binB_kernel(const int* __restrict__ staged,
                                                   const int* __restrict__ bbase,
                                                   int* __restrict__ csr,
                                                   int* __restrict__ rowptr, int N) {
    constexpr int CAP = 8192;                  // bucket mean ~5120, sigma ~72
    __shared__ int cnt[BROWS];
    __shared__ int cur[BROWS];
    __shared__ int tmp[BROWS];
    __shared__ int sorted[CAP];

    const int tid = threadIdx.x;
    const int b = blockIdx.x;
    const int r0 = b * BROWS;
    const int base = bbase[b];
    const int n = bbase[b + 1] - base;

    for (int k = tid; k < BROWS; k += 256) cnt[k] = 0;
    __syncthreads();
    for (int i = tid; i < n; i += 256)
        atomicAdd(&cnt[staged[base + i] >> 17], 1);
    __syncthreads();
    tmp[tid] = cnt[tid];
    tmp[tid + 256] = cnt[tid + 256];
    __syncthreads();
    for (int o = 1; o < BROWS; o <<= 1) {
        int t0 = (tid >= o) ? tmp[tid - o] : 0;
        int t1 = (tid + 256 >= o) ? tmp[tid + 256 - o] : 0;
        __syncthreads();
        tmp[tid] += t0;
        tmp[tid + 256] += t1;
        __syncthreads();
    }
    cur[tid] = tmp[tid] - cnt[tid];
    cur[tid + 256] = tmp[tid + 256] - cnt[tid + 256];
    if (r0 + tid < N)       rowptr[r0 + tid] = base + cur[tid];
    if (r0 + tid + 256 < N) rowptr[r0 + tid + 256] = base + cur[tid + 256];
    __syncthreads();
    for (int i = tid; i < n; i += 256) {
        int p = staged[base + i];
        int pos = atomicAdd(&cur[p >> 17], 1);
        if (pos < CAP) sorted[pos] = p & 0x1FFFF;
    }
    __syncthreads();
    for (int i = tid; i < n; i += 256)
        csr[base + i] = sorted[min(i, CAP - 1)];
}

// ---------------- fused SAGE conv ----------------
// Block = 64 dst nodes, 8 blocks/CU. 32 slots (4 waves x 8); slot owns 2 rows;
// its 8 lanes (fl) each load uint2 = 8 fp8 feats (full row = 64B = 1 line);
// 4-deep feature pipeline + csr 8-ahead; HW cvt fp8->f32 accumulate. MFMA:
// K=128 (k<64 neighbor-mean LDS tile, k>=64 bf16 self from global), B from
// global. POOL: register shfl-reduce mean-pool epilogue.
template <int OUTC, bool RELU, bool POOL>
__global__ __launch_bounds__(256, 8) void sage_kernel(
    const unsigned char* __restrict__ f8,       // [N,64] fp8 e4m3 (gather table)
    const unsigned short* __restrict__ f16,     // [N,64] bf16 (self table)
    const int* __restrict__ csr,                // src, sorted by dst
    const int* __restrict__ rowptr,
    const unsigned short* __restrict__ wc,      // [OUTC,128] bf16
    const float* __restrict__ bias,             // [OUTC] f32
    unsigned short* __restrict__ out16,         // bf16 [N,OUTC] (POOL=false)
    unsigned char* __restrict__ out8,           // fp8  [N,OUTC] (POOL=false)
    const int* __restrict__ batch,              // [N] sorted graph ids (POOL)
    float* __restrict__ pooled,                 // [G,OUTC] f32 (POOL)
    int N) {
    constexpr int LDA = 68;                    // f32 gather row stride
    __shared__ float agg[64 * LDA];            // 17.4 KB
    __shared__ int rp[65];
    __shared__ int bt[64];

    const int tid = threadIdx.x, lane = tid & 63, w = tid >> 6;
    const int base = blockIdx.x * 64;

    for (int i = tid; i < 64 * LDA; i += 256) agg[i] = 0.f;
    if (tid < 65) rp[tid] = rowptr[min(base + tid, N)];
    if (POOL && tid < 64) bt[tid] = batch[min(base + tid, N - 1)];
    __syncthreads();

    // ---- gather: slot owns 2 rows, 4-deep fp8 feature pipeline ----
    {
        const int sl = (w << 3) | (lane >> 3); // slot 0..31
        const int fl = lane & 7;               // feature octet
        int r = sl * 2;
        int e0 = rp[r];
        const int end = rp[r + 2];
        if (e0 < end) {
            const uint2* f8v = reinterpret_cast<const uint2*>(f8);
            float a0 = 0.f, a1 = 0.f, a2 = 0.f, a3 = 0.f;
            float a4 = 0.f, a5 = 0.f, a6 = 0.f, a7 = 0.f;
            int nb = rp[r + 1];
            const int em = end - 1;
            int c4_ = csr[min(e0 + 4, em)], c5_ = csr[min(e0 + 5, em)];
            int c6_ = csr[min(e0 + 6, em)], c7_ = csr[min(e0 + 7, em)];
            uint2 v0 = f8v[(size_t)csr[min(e0 + 0, em)] * 8 + fl];
            uint2 v1 = f8v[(size_t)csr[min(e0 + 1, em)] * 8 + fl];
            uint2 v2 = f8v[(size_t)csr[min(e0 + 2, em)] * 8 + fl];
            uint2 v3 = f8v[(size_t)csr[min(e0 + 3, em)] * 8 + fl];

#define FLUSH_ROW()                                                              \
    do {                                                                         \
        *reinterpret_cast<float4*>(&agg[r * LDA + fl * 8]) =                     \
            make_float4(a0, a1, a2, a3);                                         \
        *reinterpret_cast<float4*>(&agg[r * LDA + fl * 8 + 4]) =                 \
            make_float4(a4, a5, a6, a7);                                         \
        a0 = a1 = a2 = a3 = a4 = a5 = a6 = a7 = 0.f;                             \
        r++;                                                                     \
        nb = rp[r + 1];                                                          \
    } while (0)

#define PROC(VV, EI)                                                             \
    do {                                                                         \
        if ((EI) < end) {                                                        \
            while ((EI) >= nb) FLUSH_ROW();                                      \
            f32x2 d0 = fp8x2_dec<false>(VV.x);                                   \
            f32x2 d1 = fp8x2_dec<true>(VV.x);                                    \
            f32x2 d2 = fp8x2_dec<false>(VV.y);                                   \
            f32x2 d3 = fp8x2_dec<true>(VV.y);                                    \
            a0 += d0.x; a1 += d0.y; a2 += d1.x; a3 += d1.y;                      \
            a4 += d2.x; a5 += d2.y; a6 += d3.x; a7 += d3.y;                      \
        }                                                                        \
    } while (0)

            for (int e = e0; e < end; e += 4) {
                PROC(v0, e + 0);
                v0 = f8v[(size_t)c4_ * 8 + fl];
                PROC(v1, e + 1);
                v1 = f8v[(size_t)c5_ * 8 + fl];
                PROC(v2, e + 2);
                v2 = f8v[(size_t)c6_ * 8 + fl];
                PROC(v3, e + 3);
                v3 = f8v[(size_t)c7_ * 8 + fl];
                c4_ = csr[min(e + 8, em)];
                c5_ = csr[min(e + 9, em)];
                c6_ = csr[min(e + 10, em)];
                c7_ = csr[min(e + 11, em)];
            }
            // final flush of current row (untouched rows stay pre-zeroed)
            *reinterpret_cast<float4*>(&agg[r * LDA + fl * 8]) =
                make_float4(a0, a1, a2, a3);
            *reinterpret_cast<float4*>(&agg[r * LDA + fl * 8 + 4]) =
                make_float4(a4, a5, a6, a7);
#undef PROC
#undef FLUSH_ROW
        }
    }
    __syncthreads();

    // ---- MFMA phase ----
    const int hl = lane & 15, sgq = lane >> 4;
    const int row = w * 16 + hl;
    float inv = 1.0f / fmaxf((float)(rp[row + 1] - rp[row]), 1.0f);
    const float* ar = &agg[row * LDA];
    bf16x8 a[4];
    a[0] = pack8(ar + sgq * 8, inv);           // k 0..31  (neighbor mean)
    a[1] = pack8(ar + 32 + sgq * 8, inv);      // k 32..63
    int nclamp = min(base + row, N - 1);
    const unsigned short* srow = &f16[(size_t)nclamp * 64];
    a[2] = *reinterpret_cast<const bf16x8*>(&srow[sgq * 8]);        // self (bf16)
    a[3] = *reinterpret_cast<const bf16x8*>(&srow[32 + sgq * 8]);

    // per-lane D-row metadata for the register pool
    int gw0 = 0, gw1 = -1;
    int myg[4];
    bool mval[4];
    if (POOL) {
        gw0 = bt[w * 16];
        gw1 = bt[w * 16 + 15];
#pragma unroll
        for (int r = 0; r < 4; r++) {
            int lrow = w * 16 + sgq * 4 + r;
            mval[r] = (base + lrow) < N;
            myg[r] = bt[lrow];
        }
    }

    constexpr int NT = OUTC / 16;
#pragma unroll
    for (int nt = 0; nt < NT; nt++) {
        f32x4 acc = {0.f, 0.f, 0.f, 0.f};
#pragma unroll
        for (int ks = 0; ks < 4; ks++) {
            bf16x8 b = *reinterpret_cast<const bf16x8*>(
                &wc[(nt * 16 + hl) * 128 + ks * 32 + sgq * 8]);
            acc = __builtin_amdgcn_mfma_f32_16x16x32_bf16(a[ks], b, acc, 0, 0, 0);
        }
        float bv = bias[nt * 16 + hl];
        if (POOL) {
            for (int g = gw0; g <= gw1; g++) {     // wave-uniform, 1-2 iters typ.
                float s = 0.f;
#pragma unroll
                for (int r = 0; r < 4; r++) {
                    float v = acc[r] + bv;
                    if (RELU) v = fmaxf(v, 0.f);
                    s += (mval[r] && myg[r] == g) ? v : 0.f;
                }
                s += __shfl_xor(s, 16);            // reduce across sgq groups
                s += __shfl_xor(s, 32);
                if (lane < 16) atomicAdd(&pooled[g * OUTC + nt * 16 + lane], s);
            }
        } else {
#pragma unroll
            for (int r = 0; r < 4; r++) {
                int node = base + w * 16 + sgq * 4 + r;   // D row = sgq*4+r
                if (node < N) {
                    float v = acc[r] + bv;
                    if (RELU) v = fmaxf(v, 0.f);
                    int oc = nt * 16 + hl;                // D col = lane&15
                    out16[(size_t)node * OUTC + oc] = f2b(v);
                    out8[(size_t)node * OUTC + oc] = f2fp8(v);
                }
            }
        }
    }
}

// ---------------- cnt via binary search over sorted batch ----------------
__global__ __launch_bounds__(128) void cnt_kernel(const int* __restrict__ batch,
                                                  float* __restrict__ cnt, int N) {
    int g = threadIdx.x;
    int lo = 0, hi = N;
    while (lo < hi) { int m = (lo + hi) >> 1; if (batch[m] < g) lo = m + 1; else hi = m; }
    int a = lo;
    lo = 0; hi = N;
    while (lo < hi) { int m = (lo + hi) >> 1; if (batch[m] < g + 1) lo = m + 1; else hi = m; }
    cnt[g] = (float)(lo - a);
}

__global__ __launch_bounds__(256) void finalize_kernel(const float* __restrict__ pooled,
                                                       const float* __restrict__ cnt,
                                                       float* __restrict__ out, int total) {
    int t = blockIdx.x * 256 + threadIdx.x;
    if (t < total) out[t] = pooled[t] / fmaxf(cnt[t >> 7], 1.0f);
}

extern "C" void kernel_launch(void* const* d_in, const int* in_sizes, int n_in,
                              void* d_out, int out_size, void* d_ws, size_t ws_size,
                              hipStream_t stream) {
    const float* x    = (const float*)d_in[0];
    const int*   ei   = (const int*)d_in[1];
    const int*   bat  = (const int*)d_in[2];
    const float* Wl1  = (const float*)d_in[3];
    const float* Wr1  = (const float*)d_in[4];
    const float* b1   = (const float*)d_in[5];
    const float* Wl2  = (const float*)d_in[6];
    const float* Wr2  = (const float*)d_in[7];
    const float* b2   = (const float*)d_in[8];
    float* out = (float*)d_out;

    const int N = in_sizes[0] / IN_CH;        // 100000
    const int E = in_sizes[1] / 2;            // 1000000
    const int* srcp = ei;
    const int* dstp = ei + E;
    const int NBUCK = (N + BROWS - 1) >> NBUCK_SHIFT;   // 196

    // workspace layout (256B aligned); total ~45 MB
    char* ws = (char*)d_ws;
    size_t off = 0;
    auto alloc = [&](size_t bytes) { size_t p = off; off += (bytes + 255) & ~255ull; return p; };
    size_t btot_off   = alloc(256 * 4);                       // zeroed
    size_t cnt_off    = alloc((size_t)N_GRAPHS * 4);          // zeroed
    size_t pooled_off = alloc((size_t)N_GRAPHS * OUT_CH * 4); // zeroed
    size_t zero_end   = off;
    size_t bbase_off  = alloc(256 * 4);
    size_t bcur_off   = alloc(256 * 4);
    size_t xb16_off   = alloc((size_t)N * 64 * 2);            // x bf16 (self)
    size_t xb8_off    = alloc((size_t)N * 64);                // x fp8 (gather)
    size_t hb16_off   = alloc((size_t)N * 64 * 2);            // h bf16 (self)
    size_t hb8_off    = alloc((size_t)N * 64);                // h fp8 (gather)
    size_t rowptr_off = alloc((size_t)(N + 1) * 4);
    size_t staged_off = alloc((size_t)E * 4);                 // packed (row<<17)|src
    size_t csr_off    = alloc((size_t)E * 4);                 // src only
    size_t wc1_off    = alloc((size_t)64 * 128 * 2);
    size_t wc2_off    = alloc((size_t)128 * 128 * 2);
    (void)ws_size;

    int*            btot   = (int*)(ws + btot_off);
    float*          cnt    = (float*)(ws + cnt_off);
    float*          pooled = (float*)(ws + pooled_off);
    int*            bbase  = (int*)(ws + bbase_off);
    int*            bcur   = (int*)(ws + bcur_off);
    unsigned short* xb16   = (unsigned short*)(ws + xb16_off);
    unsigned char*  xb8    = (unsigned char*)(ws + xb8_off);
    unsigned short* hb16   = (unsigned short*)(ws + hb16_off);
    unsigned char*  hb8    = (unsigned char*)(ws + hb8_off);
    int*            rowptr = (int*)(ws + rowptr_off);
    int*            staged = (int*)(ws + staged_off);
    int*            csr    = (int*)(ws + csr_off);
    unsigned short* wc1    = (unsigned short*)(ws + wc1_off);
    unsigned short* wc2    = (unsigned short*)(ws + wc2_off);

    (void)hipMemsetAsync(ws, 0, zero_end, stream);

    // prep (x->bf16+fp8, weights) + fused bucket-count
    const int n4 = N * 64 / 4;
    const int prep_total = n4 + 64 * 128 + 128 * 128;
    const int prep_blocks = (prep_total + 255) / 256;
    const int nch = (E + 4095) / 4096;
    prep_kernel<<<prep_blocks + nch, 256, 0, stream>>>(
        x, Wl1, Wr1, Wl2, Wr2, xb16, xb8, wc1, wc2, dstp, btot, E, n4, prep_blocks);

    // CSR build
    bucket_scan_kernel<<<1, 256, 0, stream>>>(btot, bbase, bcur, rowptr, NBUCK, N, E);
    binA_kernel<<<nch, 256, 0, stream>>>(srcp, dstp, bcur, staged, E);
    binB_kernel<<<NBUCK, 256, 0, stream>>>(staged, bbase, csr, rowptr, N);

    // fused convs
    const int nblk = (N + 63) / 64;
    sage_kernel<64, true, false><<<nblk, 256, 0, stream>>>(
        xb8, xb16, csr, rowptr, wc1, b1, hb16, hb8, nullptr, nullptr, N);
    sage_kernel<128, false, true><<<nblk, 256, 0, stream>>>(
        hb8, hb16, csr, rowptr, wc2, b2, nullptr, nullptr, bat, pooled, N);

    // finalize
    cnt_kernel<<<1, 128, 0, stream>>>(bat, cnt, N);
    finalize_kernel<<<(N_GRAPHS * OUT_CH + 255) / 256, 256, 0, stream>>>(
        pooled, cnt, out, N_GRAPHS * OUT_CH);
}